// Round 4
// baseline (177.042 us; speedup 1.0000x reference)
//
#include <hip/hip_runtime.h>
#include <hip/hip_bf16.h>
#include <math.h>

#define B_   8
#define C_   512
#define H_   96
#define W_   96
#define HW   9216
#define K_   64
#define PH   12
#define PW   12
#define NT   64     // n-tile per block in main kernel
#define CCH  64     // c-chunk
#define NBLK 144    // n-blocks per batch = HW/NT

// ws layout (bytes). candV/candN alias the dead `part` region.
#define OFF_PARTIAL 0u                    // float[8][73728]  -- dead after k_select
#define OFF_CANDV   0u                    // float[512*NBLK]
#define OFF_CANDN   294912u               // int[512*NBLK]
#define OFF_DESC    2359296u              // float[B*C*K] layout [b][c][k]
#define OFF_ROWA    3407872u              // int[512]
#define OFF_COLA    3409920u              // int[512]
#define OFF_FLATA   3411968u              // int[512]
#define OFF_OFFR    3414016u              // int[512]
#define OFF_OFFC    3416064u              // int[512]

// ---------------- kernel 1: partial channel sums (float4) ----------------
__global__ __launch_bounds__(256) void k_partial(const float* __restrict__ A,
                                                 float* __restrict__ part) {
    int idx4 = blockIdx.x * 256 + threadIdx.x;     // float4 index over b*HW/4
    int chunk = blockIdx.y;
    int b = idx4 / (HW / 4), hw4 = idx4 - b * (HW / 4);
    const float* p = A + ((size_t)(b * C_ + chunk * 64)) * HW + hw4 * 4;
    float4 s = make_float4(0.f, 0.f, 0.f, 0.f);
#pragma unroll
    for (int i = 0; i < 64; ++i) {
        float4 v = *(const float4*)&p[(size_t)i * HW];
        s.x += v.x; s.y += v.y; s.z += v.z; s.w += v.w;
    }
    *(float4*)&part[chunk * (B_ * HW) + b * HW + hw4 * 4] = s;
}

// ---------------- kernel 2: per-region argmax (first max) ----------------
__global__ void k_select(const float* __restrict__ part, int* __restrict__ rowA,
                         int* __restrict__ colA, int* __restrict__ flatA) {
    int k = blockIdx.x, b = blockIdx.y, lane = threadIdx.x;
    int gi = k >> 3, gj = k & 7;
    float bv = -1e30f; int bp = 1 << 20;
    for (int p = lane; p < PH * PW; p += 64) {
        int lr = p / PW, lc = p - lr * PW;
        int hw = (gi * PH + lr) * W_ + gj * PW + lc;
        float v = 0.f;
#pragma unroll
        for (int ch = 0; ch < 8; ++ch) v += part[ch * (B_ * HW) + b * HW + hw];
        if (v > bv || (v == bv && p < bp)) { bv = v; bp = p; }
    }
    for (int m = 1; m < 64; m <<= 1) {
        float ov = __shfl_xor(bv, m);
        int   op = __shfl_xor(bp, m);
        if (ov > bv || (ov == bv && op < bp)) { bv = ov; bp = op; }
    }
    if (lane == 0) {
        int lr = bp / PW, lc = bp - lr * PW;
        int r = gi * PH + lr, c = gj * PW + lc;
        rowA[b * K_ + k] = r; colA[b * K_ + k] = c; flatA[b * K_ + k] = r * W_ + c;
    }
}

// ---------------- kernel 3: gather descriptors desc[b][c][k] ----------------
__global__ __launch_bounds__(256) void k_gather(const float* __restrict__ A,
                                                const int* __restrict__ flatA,
                                                float* __restrict__ desc) {
    int idx = blockIdx.x * 256 + threadIdx.x;   // b(3b)|c(9b)|k(6b)
    int k = idx & 63, c = (idx >> 6) & 511, b = idx >> 15;
    desc[idx] = A[((size_t)(b * C_ + c)) * HW + flatA[(b << 6) + k]];
}

// ---------------- kernel 4: cross GEMM + fused argmin ----------------
// grid (NBLK=144, 8 batches), block 128 (2 waves). Thread tile: 8 k x 4 n.
// kg=tid>>4 (0..7): k = kg*8+kk. ng=tid&15: n = nb + ng*4 + j.
// Single 32KB LDS buffer, register double-buffered staging (T14):
// loads for chunk t+2 are issued during the write phase of chunk t+1,
// so HBM latency hides under a full 64-c compute phase.
__global__ __launch_bounds__(128) void k_main(const float* __restrict__ FB,
                                              const float* __restrict__ desc,
                                              float* __restrict__ candV,
                                              int* __restrict__ candN) {
    __shared__ float smem[8192];           // fbs [64][64] | dsk [64][64]  = 32 KB
    float* fbs = smem;                     // [c][n]
    float* dsk = smem + 4096;              // [c][k]
    int b = blockIdx.y, nb = blockIdx.x * NT;
    int tid = threadIdx.x;
    int kg = tid >> 4, ng = tid & 15;
    const int rofs = tid >> 4;             // c-row offset within 8-row stripes
    const int colb = (tid & 15) * 4;       // column quad (n or k)
    const size_t baseB = (size_t)b * C_ * HW + nb;
    const float* descb = desc + (size_t)b * C_ * K_;

    float acc[8][4];
#pragma unroll
    for (int i = 0; i < 8; ++i)
#pragma unroll
        for (int j = 0; j < 4; ++j) acc[i][j] = 0.f;
    float4 sq4 = make_float4(0.f, 0.f, 0.f, 0.f);
    float4 rfb[8], rds[8];

#define ISSUE(c0)                                                            \
    do {                                                                     \
        _Pragma("unroll")                                                    \
        for (int i = 0; i < 8; ++i) {                                        \
            int c = (c0) + i * 8 + rofs;                                     \
            rfb[i] = *(const float4*)&FB[baseB + (size_t)c * HW + colb];     \
            rds[i] = *(const float4*)&descb[(size_t)c * K_ + colb];          \
        }                                                                    \
    } while (0)

#define WRITE()                                                              \
    do {                                                                     \
        _Pragma("unroll")                                                    \
        for (int i = 0; i < 8; ++i) {                                        \
            int cr = i * 8 + rofs;                                           \
            *(float4*)&fbs[cr * 64 + colb] = rfb[i];                         \
            sq4.x = fmaf(rfb[i].x, rfb[i].x, sq4.x);                         \
            sq4.y = fmaf(rfb[i].y, rfb[i].y, sq4.y);                         \
            sq4.z = fmaf(rfb[i].z, rfb[i].z, sq4.z);                         \
            sq4.w = fmaf(rfb[i].w, rfb[i].w, sq4.w);                         \
            *(float4*)&dsk[cr * 64 + colb] = rds[i];                         \
        }                                                                    \
    } while (0)

    ISSUE(0);
    WRITE();
    ISSUE(CCH);
    __syncthreads();

    for (int t = 0; t < C_ / CCH; ++t) {
#pragma unroll 8
        for (int c = 0; c < CCH; ++c) {
            const float4 d0 = *(const float4*)&dsk[c * 64 + kg * 8];
            const float4 d1 = *(const float4*)&dsk[c * 64 + kg * 8 + 4];
            const float4 f0 = *(const float4*)&fbs[c * 64 + ng * 4];
            float dk[8] = {d0.x, d0.y, d0.z, d0.w, d1.x, d1.y, d1.z, d1.w};
            float fn[4] = {f0.x, f0.y, f0.z, f0.w};
#pragma unroll
            for (int kk = 0; kk < 8; ++kk)
#pragma unroll
                for (int j = 0; j < 4; ++j)
                    acc[kk][j] = fmaf(dk[kk], fn[j], acc[kk][j]);
        }
        __syncthreads();
        if (t < C_ / CCH - 1) {
            WRITE();                       // stage chunk t+1 (regs -> LDS)
            if (t < C_ / CCH - 2) ISSUE((t + 2) * CCH);
            __syncthreads();
        }
    }

    // fbsq reduce: reuse dsk region (dead) as scratch
    float4* pf = (float4*)dsk;             // [128]
    float* fbsq_s = dsk + 512 + 64;        // 64 floats
    pf[tid] = sq4;
    __syncthreads();
    if (tid < 16) {
        float4 s = make_float4(0.f, 0.f, 0.f, 0.f);
#pragma unroll
        for (int j2 = 0; j2 < 8; ++j2) {
            float4 a = pf[tid + 16 * j2];
            s.x += a.x; s.y += a.y; s.z += a.z; s.w += a.w;
        }
        *(float4*)&fbsq_s[tid * 4] = s;
    }
    __syncthreads();
    const float4 q0 = *(const float4*)&fbsq_s[ng * 4];
    float fsq[4] = {q0.x, q0.y, q0.z, q0.w};
#pragma unroll
    for (int kk = 0; kk < 8; ++kk) {
        float bv = 1e30f; int bn = 1 << 28;
#pragma unroll
        for (int j = 0; j < 4; ++j) {          // n ascending within thread
            float sc = fsq[j] - 2.f * acc[kk][j];
            int n = ng * 4 + j;
            if (sc < bv) { bv = sc; bn = n; }
        }
        for (int m = 1; m < 16; m <<= 1) {     // reduce across the 16 ng lanes
            float ov = __shfl_xor(bv, m);
            int   on = __shfl_xor(bn, m);
            if (ov < bv || (ov == bv && on < bn)) { bv = ov; bn = on; }
        }
        if (ng == 0) {
            int k = kg * 8 + kk;
            candV[(b * K_ + k) * NBLK + blockIdx.x] = bv;
            candN[(b * K_ + k) * NBLK + blockIdx.x] = nb + bn;
        }
    }
#undef ISSUE
#undef WRITE
}

// ---------------- kernel 5: cross-block argmin + offsets ----------------
// grid (64, 8), block 64. NBLK=144 candidates per (b,k).
__global__ void k_reduce(const float* __restrict__ candV, const int* __restrict__ candN,
                         const int* __restrict__ rowA, const int* __restrict__ colA,
                         int* __restrict__ offR, int* __restrict__ offC) {
    int k = blockIdx.x, b = blockIdx.y, lane = threadIdx.x;
    int base = (b * K_ + k) * NBLK;
    float bv = candV[base + lane]; int bn = candN[base + lane];
    {
        float ov = candV[base + 64 + lane]; int on = candN[base + 64 + lane];
        if (ov < bv || (ov == bv && on < bn)) { bv = ov; bn = on; }
    }
    if (lane < NBLK - 128) {
        float ov = candV[base + 128 + lane]; int on = candN[base + 128 + lane];
        if (ov < bv || (ov == bv && on < bn)) { bv = ov; bn = on; }
    }
    for (int m = 1; m < 64; m <<= 1) {
        float ov = __shfl_xor(bv, m);
        int   on = __shfl_xor(bn, m);
        if (ov < bv || (ov == bv && on < bn)) { bv = ov; bn = on; }
    }
    if (lane == 0) {
        int rB = bn / W_, cB = bn - rB * W_;
        offR[b * K_ + k] = rowA[b * K_ + k] - rB;   // -(rowB - rowA)
        offC[b * K_ + k] = colA[b * K_ + k] - cB;
    }
}

// ---------------- kernel 6: per-batch mode (first-index tie-break) ----------------
__global__ void k_mode(const int* __restrict__ offR, const int* __restrict__ offC,
                       int* __restrict__ out) {
    __shared__ int r_s[64], c_s[64];
    int b = blockIdx.x, k = threadIdx.x;
    r_s[k] = offR[b * 64 + k]; c_s[k] = offC[b * 64 + k];
    __syncthreads();
    int mr = r_s[k], mc = c_s[k], cnt = 0;
#pragma unroll
    for (int j = 0; j < 64; ++j) cnt += (r_s[j] == mr && c_s[j] == mc) ? 1 : 0;
    int bk = k, bc = cnt;
    for (int m = 1; m < 64; m <<= 1) {
        int oc = __shfl_xor(bc, m);
        int ok = __shfl_xor(bk, m);
        if (oc > bc || (oc == bc && ok < bk)) { bc = oc; bk = ok; }
    }
    if (k == 0) { out[b * 2] = r_s[bk]; out[b * 2 + 1] = c_s[bk]; }
}

extern "C" void kernel_launch(void* const* d_in, const int* in_sizes, int n_in,
                              void* d_out, int out_size, void* d_ws, size_t ws_size,
                              hipStream_t stream) {
    const float* A  = (const float*)d_in[0];
    const float* FB = (const float*)d_in[1];
    char* ws = (char*)d_ws;
    float* part  = (float*)(ws + OFF_PARTIAL);
    float* desc  = (float*)(ws + OFF_DESC);
    int*   rowA  = (int*)(ws + OFF_ROWA);
    int*   colA  = (int*)(ws + OFF_COLA);
    int*   flatA = (int*)(ws + OFF_FLATA);
    float* candV = (float*)(ws + OFF_CANDV);
    int*   candN = (int*)(ws + OFF_CANDN);
    int*   offR  = (int*)(ws + OFF_OFFR);
    int*   offC  = (int*)(ws + OFF_OFFC);
    int*   out   = (int*)d_out;

    k_partial<<<dim3((B_ * HW) / 1024, 8), 256, 0, stream>>>(A, part);
    k_select<<<dim3(K_, B_), 64, 0, stream>>>(part, rowA, colA, flatA);
    k_gather<<<dim3((B_ * C_ * K_) / 256), 256, 0, stream>>>(A, flatA, desc);
    k_main<<<dim3(NBLK, B_), 128, 0, stream>>>(FB, desc, candV, candN);
    k_reduce<<<dim3(K_, B_), 64, 0, stream>>>(candV, candN, rowA, colA, offR, offC);
    k_mode<<<dim3(B_), 64, 0, stream>>>(offR, offC, out);
}

// Round 5
// 147.139 us; speedup vs baseline: 1.2032x; 1.2032x over previous
//
#include <hip/hip_runtime.h>
#include <hip/hip_bf16.h>
#include <math.h>

#define B_   8
#define C_   512
#define H_   96
#define W_   96
#define HW   9216
#define K_   64
#define PH   12
#define PW   12
#define NT   64     // n-tile per block in main kernel
#define CCH  32     // c-chunk
#define NBLK 144    // n-blocks per batch = HW/NT

// ws layout (bytes). candV/candN alias the dead `part` region.
#define OFF_PARTIAL 0u                    // float[8][73728]  -- dead after k_select
#define OFF_CANDV   0u                    // float[512*NBLK]
#define OFF_CANDN   294912u               // int[512*NBLK]
#define OFF_DESC    2359296u              // float[B*C*K] layout [b][c][k]
#define OFF_ROWA    3407872u              // int[512]
#define OFF_COLA    3409920u              // int[512]
#define OFF_FLATA   3411968u              // int[512]
#define OFF_OFFR    3414016u              // int[512]
#define OFF_OFFC    3416064u              // int[512]

#define GLOAD_LDS16(g, l)                                                     \
    __builtin_amdgcn_global_load_lds(                                         \
        (const __attribute__((address_space(1))) unsigned int*)(g),           \
        (__attribute__((address_space(3))) unsigned int*)(l), 16, 0, 0)

// ---------------- kernel 1: partial channel sums (float4) ----------------
__global__ __launch_bounds__(256) void k_partial(const float* __restrict__ A,
                                                 float* __restrict__ part) {
    int idx4 = blockIdx.x * 256 + threadIdx.x;     // float4 index over b*HW/4
    int chunk = blockIdx.y;
    int b = idx4 / (HW / 4), hw4 = idx4 - b * (HW / 4);
    const float* p = A + ((size_t)(b * C_ + chunk * 64)) * HW + hw4 * 4;
    float4 s = make_float4(0.f, 0.f, 0.f, 0.f);
#pragma unroll
    for (int i = 0; i < 64; ++i) {
        float4 v = *(const float4*)&p[(size_t)i * HW];
        s.x += v.x; s.y += v.y; s.z += v.z; s.w += v.w;
    }
    *(float4*)&part[chunk * (B_ * HW) + b * HW + hw4 * 4] = s;
}

// ---------------- kernel 2: per-region argmax (first max) ----------------
__global__ void k_select(const float* __restrict__ part, int* __restrict__ rowA,
                         int* __restrict__ colA, int* __restrict__ flatA) {
    int k = blockIdx.x, b = blockIdx.y, lane = threadIdx.x;
    int gi = k >> 3, gj = k & 7;
    float bv = -1e30f; int bp = 1 << 20;
    for (int p = lane; p < PH * PW; p += 64) {
        int lr = p / PW, lc = p - lr * PW;
        int hw = (gi * PH + lr) * W_ + gj * PW + lc;
        float v = 0.f;
#pragma unroll
        for (int ch = 0; ch < 8; ++ch) v += part[ch * (B_ * HW) + b * HW + hw];
        if (v > bv || (v == bv && p < bp)) { bv = v; bp = p; }
    }
    for (int m = 1; m < 64; m <<= 1) {
        float ov = __shfl_xor(bv, m);
        int   op = __shfl_xor(bp, m);
        if (ov > bv || (ov == bv && op < bp)) { bv = ov; bp = op; }
    }
    if (lane == 0) {
        int lr = bp / PW, lc = bp - lr * PW;
        int r = gi * PH + lr, c = gj * PW + lc;
        rowA[b * K_ + k] = r; colA[b * K_ + k] = c; flatA[b * K_ + k] = r * W_ + c;
    }
}

// ---------------- kernel 3: gather descriptors desc[b][c][k] ----------------
__global__ __launch_bounds__(256) void k_gather(const float* __restrict__ A,
                                                const int* __restrict__ flatA,
                                                float* __restrict__ desc) {
    int idx = blockIdx.x * 256 + threadIdx.x;   // b(3b)|c(9b)|k(6b)
    int k = idx & 63, c = (idx >> 6) & 511, b = idx >> 15;
    desc[idx] = A[((size_t)(b * C_ + c)) * HW + flatA[(b << 6) + k]];
}

// ---------------- kernel 4: cross GEMM + fused argmin ----------------
// grid (NBLK=144, 8 batches), block 128 (2 waves). Thread tile: 8 k x 4 n.
// kg=tid>>4 (0..7): k = kg*8+kk. ng=tid&15: n = nb + ng*4 + j.
// Double-buffered LDS staged by global_load_lds width=16 (no staging VGPRs,
// no staging VALU). Loads for chunk t+1 issue BEFORE compute(t); the
// compiler's pre-barrier vmcnt(0) drain is covered by the ~2048-cyc compute.
// Buffer layout (floats): buf = { fbs[32][64], dsk[32][64] } = 4096 floats.
__global__ __launch_bounds__(128) void k_main(const float* __restrict__ FB,
                                              const float* __restrict__ desc,
                                              float* __restrict__ candV,
                                              int* __restrict__ candN) {
    __shared__ float smem[8192];           // two 16KB buffers = 32 KB
    int b = blockIdx.y, nb = blockIdx.x * NT;
    int tid = threadIdx.x;
    int kg = tid >> 4, ng = tid & 15;
    int w = tid >> 6;                      // wave id (0,1) -- wave-uniform
    int lane = tid & 63;
    const size_t baseB = (size_t)b * C_ * HW + nb;
    const float* descb = desc + (size_t)b * C_ * K_;

    // per-lane source row/col for staging: each 1KB load covers 4 c-rows of 64 f32
    const int s_cr = (lane >> 4);          // row within the 4-row group
    const int s_nc = (lane & 15) * 4;      // column quad

    float acc[8][4];
#pragma unroll
    for (int i = 0; i < 8; ++i)
#pragma unroll
        for (int j = 0; j < 4; ++j) acc[i][j] = 0.f;
    float sqa = 0.f;
    const int sq_n = tid & 63;             // fbsq column owned by this thread
    const int sq_c0 = (tid >> 6) * 16;     // half of the c-range per chunk

#define STAGE(bufofs, c0)                                                     \
    do {                                                                      \
        _Pragma("unroll")                                                     \
        for (int i = 0; i < 4; ++i) {                                         \
            int cr = (w * 4 + i) * 4 + s_cr;                                  \
            GLOAD_LDS16(&FB[baseB + (size_t)((c0) + cr) * HW + s_nc],         \
                        &smem[(bufofs) + (w * 4 + i) * 256 + 0]);             \
            GLOAD_LDS16(&descb[(size_t)((c0) + cr) * K_ + s_nc],              \
                        &smem[(bufofs) + 2048 + (w * 4 + i) * 256 + 0]);      \
        }                                                                     \
    } while (0)

    STAGE(0, 0);
    __syncthreads();

    for (int t = 0; t < C_ / CCH; ++t) {
        const int cur = (t & 1) ? 4096 : 0;
        if (t < C_ / CCH - 1) STAGE(cur ^ 4096, (t + 1) * CCH);
        const float* fbs = &smem[cur];
        const float* dsk = &smem[cur + 2048];
#pragma unroll 8
        for (int c = 0; c < CCH; ++c) {
            const float4 d0 = *(const float4*)&dsk[c * 64 + kg * 8];
            const float4 d1 = *(const float4*)&dsk[c * 64 + kg * 8 + 4];
            const float4 f0 = *(const float4*)&fbs[c * 64 + ng * 4];
            float dk[8] = {d0.x, d0.y, d0.z, d0.w, d1.x, d1.y, d1.z, d1.w};
            float fn[4] = {f0.x, f0.y, f0.z, f0.w};
#pragma unroll
            for (int kk = 0; kk < 8; ++kk)
#pragma unroll
                for (int j = 0; j < 4; ++j)
                    acc[kk][j] = fmaf(dk[kk], fn[j], acc[kk][j]);
        }
        // fbsq: thread owns column sq_n, half c-range [sq_c0, sq_c0+16)
#pragma unroll
        for (int i = 0; i < 16; ++i) {
            float v = fbs[(sq_c0 + i) * 64 + sq_n];
            sqa = fmaf(v, v, sqa);
        }
        __syncthreads();
    }

    // combine fbsq halves: pf in smem[0..127], fbsq_s in smem[128..191]
    smem[tid] = sqa;
    __syncthreads();
    if (tid < 64) smem[128 + tid] = smem[tid] + smem[tid + 64];
    __syncthreads();
    const float4 q0 = *(const float4*)&smem[128 + ng * 4];
    float fsq[4] = {q0.x, q0.y, q0.z, q0.w};
#pragma unroll
    for (int kk = 0; kk < 8; ++kk) {
        float bv = 1e30f; int bn = 1 << 28;
#pragma unroll
        for (int j = 0; j < 4; ++j) {          // n ascending within thread
            float sc = fsq[j] - 2.f * acc[kk][j];
            int n = ng * 4 + j;
            if (sc < bv) { bv = sc; bn = n; }
        }
        for (int m = 1; m < 16; m <<= 1) {     // reduce across the 16 ng lanes
            float ov = __shfl_xor(bv, m);
            int   on = __shfl_xor(bn, m);
            if (ov < bv || (ov == bv && on < bn)) { bv = ov; bn = on; }
        }
        if (ng == 0) {
            int k = kg * 8 + kk;
            candV[(b * K_ + k) * NBLK + blockIdx.x] = bv;
            candN[(b * K_ + k) * NBLK + blockIdx.x] = nb + bn;
        }
    }
#undef STAGE
}

// ---------------- kernel 5: cross-block argmin + offsets ----------------
// grid (64, 8), block 64. NBLK=144 candidates per (b,k).
__global__ void k_reduce(const float* __restrict__ candV, const int* __restrict__ candN,
                         const int* __restrict__ rowA, const int* __restrict__ colA,
                         int* __restrict__ offR, int* __restrict__ offC) {
    int k = blockIdx.x, b = blockIdx.y, lane = threadIdx.x;
    int base = (b * K_ + k) * NBLK;
    float bv = candV[base + lane]; int bn = candN[base + lane];
    {
        float ov = candV[base + 64 + lane]; int on = candN[base + 64 + lane];
        if (ov < bv || (ov == bv && on < bn)) { bv = ov; bn = on; }
    }
    if (lane < NBLK - 128) {
        float ov = candV[base + 128 + lane]; int on = candN[base + 128 + lane];
        if (ov < bv || (ov == bv && on < bn)) { bv = ov; bn = on; }
    }
    for (int m = 1; m < 64; m <<= 1) {
        float ov = __shfl_xor(bv, m);
        int   on = __shfl_xor(bn, m);
        if (ov < bv || (ov == bv && on < bn)) { bv = ov; bn = on; }
    }
    if (lane == 0) {
        int rB = bn / W_, cB = bn - rB * W_;
        offR[b * K_ + k] = rowA[b * K_ + k] - rB;   // -(rowB - rowA)
        offC[b * K_ + k] = colA[b * K_ + k] - cB;
    }
}

// ---------------- kernel 6: per-batch mode (first-index tie-break) ----------------
__global__ void k_mode(const int* __restrict__ offR, const int* __restrict__ offC,
                       int* __restrict__ out) {
    __shared__ int r_s[64], c_s[64];
    int b = blockIdx.x, k = threadIdx.x;
    r_s[k] = offR[b * 64 + k]; c_s[k] = offC[b * 64 + k];
    __syncthreads();
    int mr = r_s[k], mc = c_s[k], cnt = 0;
#pragma unroll
    for (int j = 0; j < 64; ++j) cnt += (r_s[j] == mr && c_s[j] == mc) ? 1 : 0;
    int bk = k, bc = cnt;
    for (int m = 1; m < 64; m <<= 1) {
        int oc = __shfl_xor(bc, m);
        int ok = __shfl_xor(bk, m);
        if (oc > bc || (oc == bc && ok < bk)) { bc = oc; bk = ok; }
    }
    if (k == 0) { out[b * 2] = r_s[bk]; out[b * 2 + 1] = c_s[bk]; }
}

extern "C" void kernel_launch(void* const* d_in, const int* in_sizes, int n_in,
                              void* d_out, int out_size, void* d_ws, size_t ws_size,
                              hipStream_t stream) {
    const float* A  = (const float*)d_in[0];
    const float* FB = (const float*)d_in[1];
    char* ws = (char*)d_ws;
    float* part  = (float*)(ws + OFF_PARTIAL);
    float* desc  = (float*)(ws + OFF_DESC);
    int*   rowA  = (int*)(ws + OFF_ROWA);
    int*   colA  = (int*)(ws + OFF_COLA);
    int*   flatA = (int*)(ws + OFF_FLATA);
    float* candV = (float*)(ws + OFF_CANDV);
    int*   candN = (int*)(ws + OFF_CANDN);
    int*   offR  = (int*)(ws + OFF_OFFR);
    int*   offC  = (int*)(ws + OFF_OFFC);
    int*   out   = (int*)d_out;

    k_partial<<<dim3((B_ * HW) / 1024, 8), 256, 0, stream>>>(A, part);
    k_select<<<dim3(K_, B_), 64, 0, stream>>>(part, rowA, colA, flatA);
    k_gather<<<dim3((B_ * C_ * K_) / 256), 256, 0, stream>>>(A, flatA, desc);
    k_main<<<dim3(NBLK, B_), 128, 0, stream>>>(FB, desc, candV, candN);
    k_reduce<<<dim3(K_, B_), 64, 0, stream>>>(candV, candN, rowA, colA, offR, offC);
    k_mode<<<dim3(B_), 64, 0, stream>>>(offR, offC, out);
}